// Round 4
// baseline (761.203 us; speedup 1.0000x reference)
//
#include <hip/hip_runtime.h>

#define NB 65536

typedef unsigned long long u64;
typedef __attribute__((ext_vector_type(8))) short short8;   // 8 bf16
typedef __attribute__((ext_vector_type(4))) float f32x4;

union FragAB { unsigned short us[8]; unsigned w[4]; short8 v; };

__device__ __forceinline__ float sigf(float x){ return 1.0f/(1.0f + __expf(-x)); }
__device__ __forceinline__ float tanh_fast(float x){ return 1.0f - 2.0f/(1.0f + __expf(2.0f*x)); }

__device__ __forceinline__ unsigned short f2bf(float f){
    union { float f; unsigned u; } x; x.f = f;
    unsigned r = x.u + 0x7FFFu + ((x.u >> 16) & 1u);   // RNE
    return (unsigned short)(r >> 16);
}
__device__ __forceinline__ float bf2f(unsigned short h){
    union { unsigned u; float f; } x; x.u = ((unsigned)h) << 16; return x.f;
}

// ============ Kernel 1: fused conv+LIF, producer/consumer pipelined ============
// Block = 320 threads = 5 waves, 64 samples (lane = sample).
// Waves 0-3: conv1+bn1+relu -> conv2 (raw acc) for 11 positions/superstep (split 3/3/3/2)
//            into LDS chunk h2s[132][64] (lane-consecutive => <=2-way banks, free).
// Wave 4:    sequential LIF scan (m1/m2 in registers, site index compile-time via
//            132-unroll), BN2+relu applied here, packs spikes, accumulates avg.
__global__ __launch_bounds__(320, 3)
void k_conv_lif(const float* __restrict__ x,
                const float* __restrict__ c1w, const float* __restrict__ c1b,
                const float* __restrict__ b1g, const float* __restrict__ b1b,
                const float* __restrict__ b1m, const float* __restrict__ b1v,
                const float* __restrict__ c2w, const float* __restrict__ c2b,
                const float* __restrict__ b2g, const float* __restrict__ b2b,
                const float* __restrict__ b2m, const float* __restrict__ b2v,
                u64* __restrict__ spk,
                float* __restrict__ avg)
{
    __shared__ float h2s[132][64];     // raw conv2 accs for one 11-position chunk

    const int tid  = threadIdx.x;
    const int lane = tid & 63;
    const int wv   = __builtin_amdgcn_readfirstlane(tid >> 6);  // 0..4
    const int b    = blockIdx.x * 64 + lane;
    const float* xr = x + (size_t)b * 360;

    // ---- producer constants (waves 0-3): conv1 folded with bn1 ----
    float w1f[6][5], c1f[6];
    // ---- consumer constants/state (wave 4) ----
    float m1[33], m2[33], sum12[12], s2v[12], t2v[12];

    if (wv < 4) {
        #pragma unroll
        for (int c = 0; c < 6; ++c) {
            float s = b1g[c] / sqrtf(b1v[c] + 1e-5f);
            #pragma unroll
            for (int j = 0; j < 5; ++j) w1f[c][j] = c1w[c*5+j] * s;
            c1f[c] = (c1b[c] - b1m[c]) * s + b1b[c];
        }
    } else {
        #pragma unroll
        for (int c = 0; c < 12; ++c) {
            float s = b2g[c] / sqrtf(b2v[c] + 1e-5f);
            s2v[c] = s;
            t2v[c] = (c2b[c] - b2m[c]) * s + b2b[c];
            sum12[c] = 0.f;
        }
        #pragma unroll
        for (int k = 0; k < 33; ++k) { m1[k] = 0.f; m2[k] = 0.f; }
    }

    const int p0o  = 3 * wv;                // producer position offset in superstep
    const int npos = (wv == 3) ? 2 : 3;

    #pragma unroll 1
    for (int ss = 0; ss < 8; ++ss) {
        if (wv < 4) {
            const int p0    = 11*ss + p0o;
            const int xbase = 4*p0 - 4;
            float xw[20];
            #pragma unroll
            for (int e = 0; e < 5; ++e) {
                const int gi = xbase + 4*e;      // max 4*86-4+16 = 356 -> in range
                float4 v;
                if (gi >= 0) v = *(const float4*)(xr + gi);
                else         v = make_float4(0.f,0.f,0.f,0.f);
                xw[4*e+0]=v.x; xw[4*e+1]=v.y; xw[4*e+2]=v.z; xw[4*e+3]=v.w;
            }
            // rolling h1 cols: hA = col 2p-1, hB = 2p, hC = 2p+1
            float hA[6], hB[6], hC[6];
            {
                const bool valid = (2*p0 - 1) >= 0;   // false only ss=0,wv=0
                #pragma unroll
                for (int c = 0; c < 6; ++c) {
                    float a = c1f[c] + w1f[c][0]*xw[0] + w1f[c][1]*xw[1]
                            + w1f[c][2]*xw[2] + w1f[c][3]*xw[3] + w1f[c][4]*xw[4];
                    hA[c] = valid ? fmaxf(a, 0.f) : 0.f;
                }
            }
            #pragma unroll
            for (int pi = 0; pi < 3; ++pi) {
                if (pi < npos) {
                    #pragma unroll
                    for (int c = 0; c < 6; ++c) {
                        float aB = c1f[c] + w1f[c][0]*xw[4*pi+2] + w1f[c][1]*xw[4*pi+3]
                                 + w1f[c][2]*xw[4*pi+4] + w1f[c][3]*xw[4*pi+5] + w1f[c][4]*xw[4*pi+6];
                        float aC = c1f[c] + w1f[c][0]*xw[4*pi+4] + w1f[c][1]*xw[4*pi+5]
                                 + w1f[c][2]*xw[4*pi+6] + w1f[c][3]*xw[4*pi+7] + w1f[c][4]*xw[4*pi+8];
                        hB[c] = fmaxf(aB, 0.f);
                        hC[c] = fmaxf(aC, 0.f);
                    }
                    const int lsb = 36*wv + 12*pi;
                    #pragma unroll
                    for (int c2 = 0; c2 < 12; ++c2) {
                        float acc = 0.f;
                        #pragma unroll
                        for (int c1 = 0; c1 < 6; ++c1) {
                            const float* wp = c2w + c2*18 + c1*3;
                            acc += wp[0]*hA[c1] + wp[1]*hB[c1] + wp[2]*hC[c1];
                        }
                        h2s[lsb + c2][lane] = acc;
                    }
                    #pragma unroll
                    for (int c = 0; c < 6; ++c) hA[c] = hC[c];
                }
            }
        }
        __syncthreads();
        if (wv == 4) {
            unsigned curlo = 0u, curhi = 0u;
            #pragma unroll
            for (int ls = 0; ls < 132; ++ls) {
                const int kk = ls % 33;       // compile-time
                const int c2 = ls % 12;       // compile-time
                float a  = h2s[ls][lane];
                float hv = fmaxf(a*s2v[c2] + t2v[c2], 0.f);
                sum12[c2] += hv;
                float v1 = 0.95f*m1[kk] + hv;
                float sp1 = (v1 > 0.5f) ? 1.f : 0.f;
                m1[kk] = v1 * (1.f - sp1);
                float v2 = 0.9f*m2[kk] + sp1;
                bool sp2 = (v2 > 0.6f);
                m2[kk] = sp2 ? 0.f : v2;
                if (sp2) { if (kk < 32) curlo |= (1u << kk); else curhi |= 1u; }
                if (kk == 32) {
                    spk[(size_t)(4*ss + ls/33)*NB + b] = ((u64)curhi << 32) | (u64)curlo;
                    curlo = 0u; curhi = 0u;
                }
            }
        }
        __syncthreads();
    }

    // tail positions 88 (wave 0) and 89 (wave 1): avg only
    if (wv < 2) {
        const int p = 88 + wv;
        const int xbase = 4*p - 4;
        float xw[12];
        #pragma unroll
        for (int e = 0; e < 3; ++e) {
            const int gi = xbase + 4*e;
            float4 v;
            if (gi <= 356) v = *(const float4*)(xr + gi);
            else           v = make_float4(0.f,0.f,0.f,0.f);   // x[360..] = conv pad
            xw[4*e+0]=v.x; xw[4*e+1]=v.y; xw[4*e+2]=v.z; xw[4*e+3]=v.w;
        }
        float hA[6], hB[6], hC[6];
        #pragma unroll
        for (int c = 0; c < 6; ++c) {
            float aA = c1f[c] + w1f[c][0]*xw[0] + w1f[c][1]*xw[1]
                     + w1f[c][2]*xw[2] + w1f[c][3]*xw[3] + w1f[c][4]*xw[4];
            float aB = c1f[c] + w1f[c][0]*xw[2] + w1f[c][1]*xw[3]
                     + w1f[c][2]*xw[4] + w1f[c][3]*xw[5] + w1f[c][4]*xw[6];
            float aC = c1f[c] + w1f[c][0]*xw[4] + w1f[c][1]*xw[5]
                     + w1f[c][2]*xw[6] + w1f[c][3]*xw[7] + w1f[c][4]*xw[8];
            hA[c] = fmaxf(aA, 0.f);
            hB[c] = fmaxf(aB, 0.f);
            hC[c] = fmaxf(aC, 0.f);
        }
        #pragma unroll
        for (int c2 = 0; c2 < 12; ++c2) {
            float acc = 0.f;
            #pragma unroll
            for (int c1 = 0; c1 < 6; ++c1) {
                const float* wp = c2w + c2*18 + c1*3;
                acc += wp[0]*hA[c1] + wp[1]*hB[c1] + wp[2]*hC[c1];
            }
            h2s[12*wv + c2][lane] = acc;
        }
    }
    __syncthreads();
    if (wv == 4) {
        #pragma unroll
        for (int ls = 0; ls < 24; ++ls) {
            const int c2 = ls % 12;
            float a = h2s[ls][lane];
            sum12[c2] += fmaxf(a*s2v[c2] + t2v[c2], 0.f);
        }
        #pragma unroll
        for (int c = 0; c < 12; ++c) avg[(size_t)c*NB + b] = sum12[c] / 90.0f;
    }
}

// ============ Kernel 2: MFMA LSTM (split-bf16) + heads ============
// hx row stride padded 64 -> 72 shorts (144 B = 36 dwords ≡ 4 mod 32 banks):
// ds_read_b128 2-way (free), ds_write_b16 <=4-way, 16B alignment kept.
__global__ __launch_bounds__(256, 2)
void k_lstm_mfma(const u64* __restrict__ spk,
                 const float* __restrict__ avg,
                 const float* __restrict__ wih, const float* __restrict__ whh,
                 const float* __restrict__ bih, const float* __restrict__ bhh,
                 const float* __restrict__ rw1, const float* __restrict__ rb1,
                 const float* __restrict__ rw2, const float* __restrict__ rb2,
                 const float* __restrict__ fw,  const float* __restrict__ fb,
                 const float* __restrict__ cw1, const float* __restrict__ cb1,
                 const float* __restrict__ cw2, const float* __restrict__ cb2,
                 float* __restrict__ out)
{
    __shared__ unsigned short hx[4][16][72];  // [n][0..23]=h_hi, [32..55]=h_lo, rest 0
    __shared__ float hf[4][16][24];           // final h fp32 for heads

    const int tid  = threadIdx.x;
    const int lane = tid & 63;
    const int wv   = __builtin_amdgcn_readfirstlane(tid >> 6);
    const int q    = lane >> 4;
    const int n16  = lane & 15;
    const int sample = blockIdx.x * 64 + wv * 16 + n16;

    // zero this wave's hx region: 16*72 shorts = 576 u32 = 9/lane
    {
        unsigned* zp = (unsigned*)&hx[wv][0][0];
        #pragma unroll
        for (int i = 0; i < 9; ++i) zp[lane + 64*i] = 0u;
    }

    // ---- load A fragments (weights), one-time ----
    short8 WihHi[6][2], WihLo[6], WhhHi[6], WhhLo[6];
    #pragma unroll
    for (int m = 0; m < 6; ++m) {
        const int rowA = 16*m + n16;
        const int u    = rowA >> 2;
        const int gt   = rowA & 3;
        const float* wr = wih + (gt*24 + u)*33;
        FragAB fh, fl;
        #pragma unroll
        for (int j = 0; j < 8; ++j) {
            float v = wr[q*8 + j];
            unsigned short h = f2bf(v);
            fh.us[j] = h;
            fl.us[j] = f2bf(v - bf2f(h));
        }
        WihHi[m][0] = fh.v; WihLo[m] = fl.v;
        FragAB f1;
        #pragma unroll
        for (int j = 0; j < 8; ++j) f1.us[j] = 0;
        if (q == 0) f1.us[0] = f2bf(wr[32]);
        WihHi[m][1] = f1.v;

        const float* hr = whh + (gt*24 + u)*24;
        FragAB gh, gl;
        #pragma unroll
        for (int j = 0; j < 8; ++j) {
            int k = q*8 + j;
            float v = (k < 24) ? hr[k] : 0.f;
            unsigned short h = f2bf(v);
            gh.us[j] = h;
            gl.us[j] = (k < 24) ? f2bf(v - bf2f(h)) : (unsigned short)0;
        }
        WhhHi[m] = gh.v; WhhLo[m] = gl.v;
    }

    float bias[6][4];
    #pragma unroll
    for (int m = 0; m < 6; ++m) {
        const int u = 4*m + q;
        #pragma unroll
        for (int rr = 0; rr < 4; ++rr)
            bias[m][rr] = bih[rr*24 + u] + bhh[rr*24 + u];
    }

    float cst[6], hreg[6];
    #pragma unroll
    for (int m = 0; m < 6; ++m) { cst[m] = 0.f; hreg[m] = 0.f; }

    const u64* sp = spk + sample;
    u64 wcur = sp[0];
    const int q8 = q * 8;

    __asm__ volatile("s_waitcnt lgkmcnt(0)" ::: "memory");

    #pragma unroll 1
    for (int t = 0; t < 32; ++t) {
        short8 BhHi = *reinterpret_cast<const short8*>(&hx[wv][n16][q8]);
        short8 BhLo = *reinterpret_cast<const short8*>(&hx[wv][n16][32 + q8]);

        const unsigned lo32 = (unsigned)wcur;
        const unsigned hi32 = (unsigned)(wcur >> 32);
        FragAB bs0;
        {
            const unsigned byt = (lo32 >> q8) & 0xFFu;
            #pragma unroll
            for (int p = 0; p < 4; ++p) {
                unsigned e0 = (byt >> (2*p)) & 1u;
                unsigned e1 = (byt >> (2*p+1)) & 1u;
                bs0.w[p] = (e0 ? 0x3F80u : 0u) | (e1 ? 0x3F800000u : 0u);
            }
        }
        FragAB bs1;
        bs1.w[0] = (q == 0 && (hi32 & 1u)) ? 0x3F80u : 0u;
        bs1.w[1] = 0u; bs1.w[2] = 0u; bs1.w[3] = 0u;

        u64 wnext = 0;
        if (t < 31) wnext = sp[(size_t)(t+1)*NB];

        f32x4 acc[6];
        #pragma unroll
        for (int m = 0; m < 6; ++m) {
            f32x4 a; a[0]=bias[m][0]; a[1]=bias[m][1]; a[2]=bias[m][2]; a[3]=bias[m][3];
            a = __builtin_amdgcn_mfma_f32_16x16x32_bf16(WihHi[m][0], bs0.v, a, 0, 0, 0);
            a = __builtin_amdgcn_mfma_f32_16x16x32_bf16(WihLo[m],    bs0.v, a, 0, 0, 0);
            a = __builtin_amdgcn_mfma_f32_16x16x32_bf16(WihHi[m][1], bs1.v, a, 0, 0, 0);
            a = __builtin_amdgcn_mfma_f32_16x16x32_bf16(WhhHi[m],    BhHi,  a, 0, 0, 0);
            a = __builtin_amdgcn_mfma_f32_16x16x32_bf16(WhhLo[m],    BhHi,  a, 0, 0, 0);
            a = __builtin_amdgcn_mfma_f32_16x16x32_bf16(WhhHi[m],    BhLo,  a, 0, 0, 0);
            acc[m] = a;
        }

        #pragma unroll
        for (int m = 0; m < 6; ++m) {
            float ii = sigf(acc[m][0]);
            float ff = sigf(acc[m][1]);
            float gg = tanh_fast(acc[m][2]);
            float oo = sigf(acc[m][3]);
            float cn = ff*cst[m] + ii*gg;
            cst[m] = cn;
            float h = oo * tanh_fast(cn);
            hreg[m] = h;
            unsigned short hh = f2bf(h);
            unsigned short hl = f2bf(h - bf2f(hh));
            hx[wv][n16][4*m + q]      = hh;
            hx[wv][n16][32 + 4*m + q] = hl;
        }
        __asm__ volatile("s_waitcnt lgkmcnt(0)" ::: "memory");
        wcur = wnext;
    }

    #pragma unroll
    for (int m = 0; m < 6; ++m) hf[wv][n16][4*m + q] = hreg[m];
    __asm__ volatile("s_waitcnt lgkmcnt(0)" ::: "memory");

    if (lane < 16) {
        const int sm = lane;
        const int bidx = blockIdx.x * 64 + wv * 16 + sm;
        float h[24];
        #pragma unroll
        for (int u2 = 0; u2 < 24; ++u2) h[u2] = hf[wv][sm][u2];
        float av[12];
        #pragma unroll
        for (int cc = 0; cc < 12; ++cc) av[cc] = avg[(size_t)cc*NB + bidx];

        float f1[12];
        #pragma unroll
        for (int r = 0; r < 12; ++r) {
            float a = rb1[r];
            #pragma unroll
            for (int u2 = 0; u2 < 24; ++u2) a += rw1[r*36+u2]*h[u2];
            #pragma unroll
            for (int cc = 0; cc < 12; ++cc) a += rw1[r*36+24+cc]*av[cc];
            f1[r] = fmaxf(a, 0.f);
        }
        float z0 = rb2[0], z1 = rb2[1];
        #pragma unroll
        for (int r = 0; r < 12; ++r) { z0 += rw2[r]*f1[r]; z1 += rw2[12+r]*f1[r]; }
        float mz = fmaxf(z0, z1);
        float e0 = __expf(z0 - mz), e1 = __expf(z1 - mz);
        float inv = 1.0f/(e0 + e1);
        float r0 = 0.7f*e0*inv, r1 = 0.3f*e1*inv;
        float alpha = r0/(r0 + r1);

        float ha[24], sa[12];
        #pragma unroll
        for (int u2 = 0; u2 < 24; ++u2) ha[u2] = h[u2]*alpha;
        #pragma unroll
        for (int cc = 0; cc < 12; ++cc) sa[cc] = av[cc]*(1.f - alpha);

        float fu[24];
        #pragma unroll
        for (int r = 0; r < 24; ++r) {
            float a = fb[r];
            #pragma unroll
            for (int u2 = 0; u2 < 24; ++u2) a += fw[r*36+u2]*ha[u2];
            #pragma unroll
            for (int cc = 0; cc < 12; ++cc) a += fw[r*36+24+cc]*sa[cc];
            fu[r] = fmaxf(a, 0.f);
        }
        float c1o[12];
        #pragma unroll
        for (int r = 0; r < 12; ++r) {
            float a = cb1[r];
            #pragma unroll
            for (int u2 = 0; u2 < 24; ++u2) a += cw1[r*24+u2]*fu[u2];
            c1o[r] = fmaxf(a, 0.f);
        }
        #pragma unroll
        for (int o = 0; o < 5; ++o) {
            float a = cb2[o];
            #pragma unroll
            for (int r = 0; r < 12; ++r) a += cw2[o*12+r]*c1o[r];
            out[(size_t)bidx*5 + o] = a;
        }
    }
}

extern "C" void kernel_launch(void* const* d_in, const int* in_sizes, int n_in,
                              void* d_out, int out_size, void* d_ws, size_t ws_size,
                              hipStream_t stream) {
    const float* x    = (const float*)d_in[0];
    const float* c1w  = (const float*)d_in[1];
    const float* c1b  = (const float*)d_in[2];
    const float* b1g  = (const float*)d_in[3];
    const float* b1b  = (const float*)d_in[4];
    const float* b1m  = (const float*)d_in[5];
    const float* b1v  = (const float*)d_in[6];
    const float* c2w  = (const float*)d_in[7];
    const float* c2b  = (const float*)d_in[8];
    const float* b2g  = (const float*)d_in[9];
    const float* b2b  = (const float*)d_in[10];
    const float* b2m  = (const float*)d_in[11];
    const float* b2v  = (const float*)d_in[12];
    const float* wih  = (const float*)d_in[13];
    const float* whh  = (const float*)d_in[14];
    const float* bih  = (const float*)d_in[15];
    const float* bhh  = (const float*)d_in[16];
    const float* rw1  = (const float*)d_in[17];
    const float* rb1  = (const float*)d_in[18];
    const float* rw2  = (const float*)d_in[19];
    const float* rb2  = (const float*)d_in[20];
    const float* fw   = (const float*)d_in[21];
    const float* fb   = (const float*)d_in[22];
    const float* cw1  = (const float*)d_in[23];
    const float* cb1  = (const float*)d_in[24];
    const float* cw2  = (const float*)d_in[25];
    const float* cb2  = (const float*)d_in[26];
    float* out = (float*)d_out;

    u64* spk  = (u64*)d_ws;                                            // 16.78 MB
    float* avg = (float*)((char*)d_ws + (size_t)32*NB*sizeof(u64));    // 3.15 MB

    k_conv_lif<<<dim3(NB/64), dim3(320), 0, stream>>>(x, c1w, c1b, b1g, b1b, b1m, b1v,
                                                      c2w, c2b, b2g, b2b, b2m, b2v, spk, avg);
    k_lstm_mfma<<<dim3(NB/64), dim3(256), 0, stream>>>(spk, avg, wih, whh, bih, bhh,
                                                       rw1, rb1, rw2, rb2, fw, fb,
                                                       cw1, cb1, cw2, cb2, out);
}

// Round 5
// 609.726 us; speedup vs baseline: 1.2484x; 1.2484x over previous
//
#include <hip/hip_runtime.h>

#define NB 65536

typedef unsigned long long u64;
typedef __attribute__((ext_vector_type(8))) short short8;   // 8 bf16
typedef __attribute__((ext_vector_type(4))) float f32x4;

union FragAB { unsigned short us[8]; unsigned w[4]; short8 v; };

__device__ __forceinline__ float sigf(float x){ return 1.0f/(1.0f + __expf(-x)); }
__device__ __forceinline__ float tanh_fast(float x){ return 1.0f - 2.0f/(1.0f + __expf(2.0f*x)); }

__device__ __forceinline__ unsigned short f2bf(float f){
    union { float f; unsigned u; } x; x.f = f;
    unsigned r = x.u + 0x7FFFu + ((x.u >> 16) & 1u);   // RNE
    return (unsigned short)(r >> 16);
}
__device__ __forceinline__ float bf2f(unsigned short h){
    union { unsigned u; float f; } x; x.u = ((unsigned)h) << 16; return x.f;
}

// ============ Kernel 1: fused conv+LIF, double-buffered pipeline ============
// Block = 384 threads = 6 waves, 64 samples (lane = sample).
// Waves 0-3: conv1+bn1+relu -> conv2 raw accs, chunk = 11 positions (3/3/3/2 split),
//            into h2s[buf][132][64] (row stride 64 floats -> 2-way banks, free).
// Waves 4-5: LIF chains split by kk (<17 / >=17); m-state in registers,
//            site indices compile-time; spike bit partials to LDS.
// Wave 3 additionally combines+stores spike words one chunk behind.
// One barrier per iteration: produce(ss) || consume(ss-1) || combine(ss-2).
__global__ __launch_bounds__(384, 3)
void k_conv_lif(const float* __restrict__ x,
                const float* __restrict__ c1w, const float* __restrict__ c1b,
                const float* __restrict__ b1g, const float* __restrict__ b1b,
                const float* __restrict__ b1m, const float* __restrict__ b1v,
                const float* __restrict__ c2w, const float* __restrict__ c2b,
                const float* __restrict__ b2g, const float* __restrict__ b2b,
                const float* __restrict__ b2m, const float* __restrict__ b2v,
                u64* __restrict__ spk,
                float* __restrict__ avg)
{
    __shared__ float h2s[2][132][64];     // 67.6 KB, double buffer
    __shared__ unsigned pw4[2][4][64];    // wave4 spike partials (bits 0..16)
    __shared__ u64      pw5[2][4][64];    // wave5 spike partials (bits 17..32)

    const int tid  = threadIdx.x;
    const int lane = tid & 63;
    const int wv   = __builtin_amdgcn_readfirstlane(tid >> 6);  // 0..5
    const int b    = blockIdx.x * 64 + lane;
    const float* xr = x + (size_t)b * 360;

    // producer constants (waves 0-3)
    float w1f[6][5], c1f[6];
    // consumer constants/state (waves 4-5)
    float s2v[12], t2v[12], sum12[12];
    float m1[17], m2[17];

    if (wv < 4) {
        #pragma unroll
        for (int c = 0; c < 6; ++c) {
            float s = b1g[c] / sqrtf(b1v[c] + 1e-5f);
            #pragma unroll
            for (int j = 0; j < 5; ++j) w1f[c][j] = c1w[c*5+j] * s;
            c1f[c] = (c1b[c] - b1m[c]) * s + b1b[c];
        }
    } else {
        #pragma unroll
        for (int c = 0; c < 12; ++c) {
            float s = b2g[c] / sqrtf(b2v[c] + 1e-5f);
            s2v[c] = s;
            t2v[c] = (c2b[c] - b2m[c]) * s + b2b[c];
            sum12[c] = 0.f;
        }
        #pragma unroll
        for (int k = 0; k < 17; ++k) { m1[k] = 0.f; m2[k] = 0.f; }
    }

    unsigned p4 = 0u;   // wave4 running partial
    u64      p5 = 0ull; // wave5 running partial

    // producer routine: positions p0..p0+npos-1 -> dst rows lsbase..lsbase+12*npos-1
    auto produce = [&](int p0, int npos, int lsbase, float* dst) {
        const int xbase = 4*p0 - 4;
        float xw[20];
        #pragma unroll
        for (int e = 0; e < 5; ++e) {
            const int gi = xbase + 4*e;
            float4 v;
            if (gi >= 0 && gi <= 356) v = *(const float4*)(xr + gi);
            else                      v = make_float4(0.f,0.f,0.f,0.f);
            xw[4*e+0]=v.x; xw[4*e+1]=v.y; xw[4*e+2]=v.z; xw[4*e+3]=v.w;
        }
        float hA[6], hB[6], hC[6];
        {
            const bool valid = (p0 > 0);       // col 2p0-1 exists unless p0==0
            #pragma unroll
            for (int c = 0; c < 6; ++c) {
                float a = c1f[c] + w1f[c][0]*xw[0] + w1f[c][1]*xw[1]
                        + w1f[c][2]*xw[2] + w1f[c][3]*xw[3] + w1f[c][4]*xw[4];
                hA[c] = valid ? fmaxf(a, 0.f) : 0.f;
            }
        }
        #pragma unroll
        for (int pi = 0; pi < 3; ++pi) {
            if (pi < npos) {
                #pragma unroll
                for (int c = 0; c < 6; ++c) {
                    float aB = c1f[c] + w1f[c][0]*xw[4*pi+2] + w1f[c][1]*xw[4*pi+3]
                             + w1f[c][2]*xw[4*pi+4] + w1f[c][3]*xw[4*pi+5] + w1f[c][4]*xw[4*pi+6];
                    float aC = c1f[c] + w1f[c][0]*xw[4*pi+4] + w1f[c][1]*xw[4*pi+5]
                             + w1f[c][2]*xw[4*pi+6] + w1f[c][3]*xw[4*pi+7] + w1f[c][4]*xw[4*pi+8];
                    hB[c] = fmaxf(aB, 0.f);
                    hC[c] = fmaxf(aC, 0.f);
                }
                #pragma unroll
                for (int c2 = 0; c2 < 12; ++c2) {
                    float acc = 0.f;
                    #pragma unroll
                    for (int c1 = 0; c1 < 6; ++c1) {
                        const float* wp = c2w + c2*18 + c1*3;
                        acc += wp[0]*hA[c1] + wp[1]*hB[c1] + wp[2]*hC[c1];
                    }
                    dst[(lsbase + 12*pi + c2)*64 + lane] = acc;
                }
                #pragma unroll
                for (int c = 0; c < 6; ++c) hA[c] = hC[c];
            }
        }
    };

    #pragma unroll 1
    for (int ss = 0; ss < 10; ++ss) {
        // ---- produce chunk ss (chunks 0..7 full, 8 = tail positions 88/89) ----
        if (wv < 4 && ss < 9) {
            float* dst = &h2s[ss & 1][0][0];
            if (ss < 8) {
                const int npos = (wv == 3) ? 2 : 3;
                produce(11*ss + 3*wv, npos, 36*wv, dst);
            } else if (wv < 2) {
                produce(88 + wv, 1, 12*wv, dst);
            }
        }
        // ---- consume chunk ss-1 ----
        if (wv >= 4 && ss >= 1) {
            const int cc  = ss - 1;
            const int buf = cc & 1;
            const float* src = &h2s[buf][0][0];
            if (cc < 8) {
                if (wv == 4) {
                    #pragma unroll
                    for (int ls = 0; ls < 132; ++ls) {
                        const int kk = ls % 33;
                        const int c2v = ls % 12;
                        if (kk < 17) {
                            float a  = src[ls*64 + lane];
                            float hv = fmaxf(a*s2v[c2v] + t2v[c2v], 0.f);
                            sum12[c2v] += hv;
                            float v1 = 0.95f*m1[kk] + hv;
                            float sp1 = (v1 > 0.5f) ? 1.f : 0.f;
                            m1[kk] = v1 * (1.f - sp1);
                            float v2 = 0.9f*m2[kk] + sp1;
                            bool sp2 = (v2 > 0.6f);
                            m2[kk] = sp2 ? 0.f : v2;
                            if (sp2) p4 |= (1u << kk);
                        }
                        if (kk == 32) {                 // end of timestep group
                            pw4[buf][ls/33][lane] = p4;
                            p4 = 0u;
                        }
                    }
                } else {
                    #pragma unroll
                    for (int ls = 0; ls < 132; ++ls) {
                        const int kk = ls % 33;
                        const int c2v = ls % 12;
                        if (kk >= 17) {
                            const int ki = kk - 17;
                            float a  = src[ls*64 + lane];
                            float hv = fmaxf(a*s2v[c2v] + t2v[c2v], 0.f);
                            sum12[c2v] += hv;
                            float v1 = 0.95f*m1[ki] + hv;
                            float sp1 = (v1 > 0.5f) ? 1.f : 0.f;
                            m1[ki] = v1 * (1.f - sp1);
                            float v2 = 0.9f*m2[ki] + sp1;
                            bool sp2 = (v2 > 0.6f);
                            m2[ki] = sp2 ? 0.f : v2;
                            if (sp2) p5 |= (1ull << kk);
                        }
                        if (kk == 32) {
                            pw5[buf][ls/33][lane] = p5;
                            p5 = 0ull;
                        }
                    }
                }
            } else {
                // tail chunk: 24 sites, avg only (t=32 not fed to SNN)
                const int base17 = (wv == 4) ? 0 : 17;
                #pragma unroll
                for (int ls = 0; ls < 24; ++ls) {
                    const int kk = ls;           // 1056 = 32*33 -> kk = ls
                    const int c2v = ls % 12;
                    const bool mine = (wv == 4) ? (kk < 17) : (kk >= 17);
                    if (mine) {
                        float a = src[ls*64 + lane];
                        sum12[c2v] += fmaxf(a*s2v[c2v] + t2v[c2v], 0.f);
                    }
                }
                (void)base17;
            }
        }
        // ---- combine & store spikes for chunk ss-2 ----
        if (wv == 3 && ss >= 2) {
            const int cc2  = ss - 2;            // 0..7
            const int bufc = cc2 & 1;
            #pragma unroll
            for (int i = 0; i < 4; ++i) {
                u64 wrd = (u64)pw4[bufc][i][lane] | pw5[bufc][i][lane];
                spk[(size_t)(4*cc2 + i)*NB + b] = wrd;
            }
        }
        __syncthreads();
    }

    // ---- avg: combine the two consumer partial sums ----
    if (wv == 4) {
        #pragma unroll
        for (int c = 0; c < 12; ++c) h2s[0][24 + c][lane] = sum12[c];
    }
    if (wv == 5) {
        #pragma unroll
        for (int c = 0; c < 12; ++c) h2s[0][36 + c][lane] = sum12[c];
    }
    __syncthreads();
    if (wv == 0) {
        #pragma unroll
        for (int c = 0; c < 12; ++c)
            avg[(size_t)c*NB + b] = (h2s[0][24 + c][lane] + h2s[0][36 + c][lane]) / 90.0f;
    }
}

// ============ Kernel 2: MFMA LSTM (split-bf16) + heads ============
// hx row stride 80 shorts (160 B): 16B-aligned b128 reads (fixes R4's misalignment),
// bank shift 8 dwords/row -> 4-way conflicts instead of 16-way.
__global__ __launch_bounds__(256, 2)
void k_lstm_mfma(const u64* __restrict__ spk,
                 const float* __restrict__ avg,
                 const float* __restrict__ wih, const float* __restrict__ whh,
                 const float* __restrict__ bih, const float* __restrict__ bhh,
                 const float* __restrict__ rw1, const float* __restrict__ rb1,
                 const float* __restrict__ rw2, const float* __restrict__ rb2,
                 const float* __restrict__ fw,  const float* __restrict__ fb,
                 const float* __restrict__ cw1, const float* __restrict__ cb1,
                 const float* __restrict__ cw2, const float* __restrict__ cb2,
                 float* __restrict__ out)
{
    __shared__ unsigned short hx[4][16][80];  // [n][0..23]=h_hi, [32..55]=h_lo, rest 0
    __shared__ float hf[4][16][24];           // final h fp32 for heads

    const int tid  = threadIdx.x;
    const int lane = tid & 63;
    const int wv   = __builtin_amdgcn_readfirstlane(tid >> 6);
    const int q    = lane >> 4;
    const int n16  = lane & 15;
    const int sample = blockIdx.x * 64 + wv * 16 + n16;

    // zero this wave's hx region: 16*80 shorts = 640 u32 = 10/lane
    {
        unsigned* zp = (unsigned*)&hx[wv][0][0];
        #pragma unroll
        for (int i = 0; i < 10; ++i) zp[lane + 64*i] = 0u;
    }

    // ---- load A fragments (weights), one-time ----
    short8 WihHi[6][2], WihLo[6], WhhHi[6], WhhLo[6];
    #pragma unroll
    for (int m = 0; m < 6; ++m) {
        const int rowA = 16*m + n16;
        const int u    = rowA >> 2;
        const int gt   = rowA & 3;
        const float* wr = wih + (gt*24 + u)*33;
        FragAB fh, fl;
        #pragma unroll
        for (int j = 0; j < 8; ++j) {
            float v = wr[q*8 + j];
            unsigned short h = f2bf(v);
            fh.us[j] = h;
            fl.us[j] = f2bf(v - bf2f(h));
        }
        WihHi[m][0] = fh.v; WihLo[m] = fl.v;
        FragAB f1;
        #pragma unroll
        for (int j = 0; j < 8; ++j) f1.us[j] = 0;
        if (q == 0) f1.us[0] = f2bf(wr[32]);
        WihHi[m][1] = f1.v;

        const float* hr = whh + (gt*24 + u)*24;
        FragAB gh, gl;
        #pragma unroll
        for (int j = 0; j < 8; ++j) {
            int k = q*8 + j;
            float v = (k < 24) ? hr[k] : 0.f;
            unsigned short h = f2bf(v);
            gh.us[j] = h;
            gl.us[j] = (k < 24) ? f2bf(v - bf2f(h)) : (unsigned short)0;
        }
        WhhHi[m] = gh.v; WhhLo[m] = gl.v;
    }

    float bias[6][4];
    #pragma unroll
    for (int m = 0; m < 6; ++m) {
        const int u = 4*m + q;
        #pragma unroll
        for (int rr = 0; rr < 4; ++rr)
            bias[m][rr] = bih[rr*24 + u] + bhh[rr*24 + u];
    }

    float cst[6], hreg[6];
    #pragma unroll
    for (int m = 0; m < 6; ++m) { cst[m] = 0.f; hreg[m] = 0.f; }

    const u64* sp = spk + sample;
    u64 wcur = sp[0];
    const int q8 = q * 8;

    __asm__ volatile("s_waitcnt lgkmcnt(0)" ::: "memory");

    #pragma unroll 1
    for (int t = 0; t < 32; ++t) {
        short8 BhHi = *reinterpret_cast<const short8*>(&hx[wv][n16][q8]);
        short8 BhLo = *reinterpret_cast<const short8*>(&hx[wv][n16][32 + q8]);

        const unsigned lo32 = (unsigned)wcur;
        const unsigned hi32 = (unsigned)(wcur >> 32);
        FragAB bs0;
        {
            const unsigned byt = (lo32 >> q8) & 0xFFu;
            #pragma unroll
            for (int p = 0; p < 4; ++p) {
                unsigned e0 = (byt >> (2*p)) & 1u;
                unsigned e1 = (byt >> (2*p+1)) & 1u;
                bs0.w[p] = (e0 ? 0x3F80u : 0u) | (e1 ? 0x3F800000u : 0u);
            }
        }
        FragAB bs1;
        bs1.w[0] = (q == 0 && (hi32 & 1u)) ? 0x3F80u : 0u;
        bs1.w[1] = 0u; bs1.w[2] = 0u; bs1.w[3] = 0u;

        u64 wnext = 0;
        if (t < 31) wnext = sp[(size_t)(t+1)*NB];

        f32x4 acc[6];
        #pragma unroll
        for (int m = 0; m < 6; ++m) {
            f32x4 a; a[0]=bias[m][0]; a[1]=bias[m][1]; a[2]=bias[m][2]; a[3]=bias[m][3];
            a = __builtin_amdgcn_mfma_f32_16x16x32_bf16(WihHi[m][0], bs0.v, a, 0, 0, 0);
            a = __builtin_amdgcn_mfma_f32_16x16x32_bf16(WihLo[m],    bs0.v, a, 0, 0, 0);
            a = __builtin_amdgcn_mfma_f32_16x16x32_bf16(WihHi[m][1], bs1.v, a, 0, 0, 0);
            a = __builtin_amdgcn_mfma_f32_16x16x32_bf16(WhhHi[m],    BhHi,  a, 0, 0, 0);
            a = __builtin_amdgcn_mfma_f32_16x16x32_bf16(WhhLo[m],    BhHi,  a, 0, 0, 0);
            a = __builtin_amdgcn_mfma_f32_16x16x32_bf16(WhhHi[m],    BhLo,  a, 0, 0, 0);
            acc[m] = a;
        }

        #pragma unroll
        for (int m = 0; m < 6; ++m) {
            float ii = sigf(acc[m][0]);
            float ff = sigf(acc[m][1]);
            float gg = tanh_fast(acc[m][2]);
            float oo = sigf(acc[m][3]);
            float cn = ff*cst[m] + ii*gg;
            cst[m] = cn;
            float h = oo * tanh_fast(cn);
            hreg[m] = h;
            unsigned short hh = f2bf(h);
            unsigned short hl = f2bf(h - bf2f(hh));
            hx[wv][n16][4*m + q]      = hh;
            hx[wv][n16][32 + 4*m + q] = hl;
        }
        __asm__ volatile("s_waitcnt lgkmcnt(0)" ::: "memory");
        wcur = wnext;
    }

    #pragma unroll
    for (int m = 0; m < 6; ++m) hf[wv][n16][4*m + q] = hreg[m];
    __asm__ volatile("s_waitcnt lgkmcnt(0)" ::: "memory");

    if (lane < 16) {
        const int sm = lane;
        const int bidx = blockIdx.x * 64 + wv * 16 + sm;
        float h[24];
        #pragma unroll
        for (int u2 = 0; u2 < 24; ++u2) h[u2] = hf[wv][sm][u2];
        float av[12];
        #pragma unroll
        for (int cc = 0; cc < 12; ++cc) av[cc] = avg[(size_t)cc*NB + bidx];

        float f1[12];
        #pragma unroll
        for (int r = 0; r < 12; ++r) {
            float a = rb1[r];
            #pragma unroll
            for (int u2 = 0; u2 < 24; ++u2) a += rw1[r*36+u2]*h[u2];
            #pragma unroll
            for (int cc = 0; cc < 12; ++cc) a += rw1[r*36+24+cc]*av[cc];
            f1[r] = fmaxf(a, 0.f);
        }
        float z0 = rb2[0], z1 = rb2[1];
        #pragma unroll
        for (int r = 0; r < 12; ++r) { z0 += rw2[r]*f1[r]; z1 += rw2[12+r]*f1[r]; }
        float mz = fmaxf(z0, z1);
        float e0 = __expf(z0 - mz), e1 = __expf(z1 - mz);
        float inv = 1.0f/(e0 + e1);
        float r0 = 0.7f*e0*inv, r1 = 0.3f*e1*inv;
        float alpha = r0/(r0 + r1);

        float ha[24], sa[12];
        #pragma unroll
        for (int u2 = 0; u2 < 24; ++u2) ha[u2] = h[u2]*alpha;
        #pragma unroll
        for (int cc = 0; cc < 12; ++cc) sa[cc] = av[cc]*(1.f - alpha);

        float fu[24];
        #pragma unroll
        for (int r = 0; r < 24; ++r) {
            float a = fb[r];
            #pragma unroll
            for (int u2 = 0; u2 < 24; ++u2) a += fw[r*36+u2]*ha[u2];
            #pragma unroll
            for (int cc = 0; cc < 12; ++cc) a += fw[r*36+24+cc]*sa[cc];
            fu[r] = fmaxf(a, 0.f);
        }
        float c1o[12];
        #pragma unroll
        for (int r = 0; r < 12; ++r) {
            float a = cb1[r];
            #pragma unroll
            for (int u2 = 0; u2 < 24; ++u2) a += cw1[r*24+u2]*fu[u2];
            c1o[r] = fmaxf(a, 0.f);
        }
        #pragma unroll
        for (int o = 0; o < 5; ++o) {
            float a = cb2[o];
            #pragma unroll
            for (int r = 0; r < 12; ++r) a += cw2[o*12+r]*c1o[r];
            out[(size_t)bidx*5 + o] = a;
        }
    }
}

extern "C" void kernel_launch(void* const* d_in, const int* in_sizes, int n_in,
                              void* d_out, int out_size, void* d_ws, size_t ws_size,
                              hipStream_t stream) {
    const float* x    = (const float*)d_in[0];
    const float* c1w  = (const float*)d_in[1];
    const float* c1b  = (const float*)d_in[2];
    const float* b1g  = (const float*)d_in[3];
    const float* b1b  = (const float*)d_in[4];
    const float* b1m  = (const float*)d_in[5];
    const float* b1v  = (const float*)d_in[6];
    const float* c2w  = (const float*)d_in[7];
    const float* c2b  = (const float*)d_in[8];
    const float* b2g  = (const float*)d_in[9];
    const float* b2b  = (const float*)d_in[10];
    const float* b2m  = (const float*)d_in[11];
    const float* b2v  = (const float*)d_in[12];
    const float* wih  = (const float*)d_in[13];
    const float* whh  = (const float*)d_in[14];
    const float* bih  = (const float*)d_in[15];
    const float* bhh  = (const float*)d_in[16];
    const float* rw1  = (const float*)d_in[17];
    const float* rb1  = (const float*)d_in[18];
    const float* rw2  = (const float*)d_in[19];
    const float* rb2  = (const float*)d_in[20];
    const float* fw   = (const float*)d_in[21];
    const float* fb   = (const float*)d_in[22];
    const float* cw1  = (const float*)d_in[23];
    const float* cb1  = (const float*)d_in[24];
    const float* cw2  = (const float*)d_in[25];
    const float* cb2  = (const float*)d_in[26];
    float* out = (float*)d_out;

    u64* spk  = (u64*)d_ws;                                            // 16.78 MB
    float* avg = (float*)((char*)d_ws + (size_t)32*NB*sizeof(u64));    // 3.15 MB

    k_conv_lif<<<dim3(NB/64), dim3(384), 0, stream>>>(x, c1w, c1b, b1g, b1b, b1m, b1v,
                                                      c2w, c2b, b2g, b2b, b2m, b2v, spk, avg);
    k_lstm_mfma<<<dim3(NB/64), dim3(256), 0, stream>>>(spk, avg, wih, whh, bih, bhh,
                                                       rw1, rb1, rw2, rb2, fw, fb,
                                                       cw1, cb1, cw2, cb2, out);
}